// Round 1
// baseline (372.908 us; speedup 1.0000x reference)
//
#include <hip/hip_runtime.h>

#define H_IMG 128
#define W_IMG 48
#define CIN   64
#define DM    32
#define NH    8
#define DH    4
#define NPIX  (H_IMG * W_IMG)   // 6144

// 0.5 (dh^-0.5) * log2(e): fold exp->exp2 conversion into q
#define Q_SCALE 0.7213475204444817f

// ---------------------------------------------------------------------------
// Kernel 1: fused QKV 3x3 SAME conv.  thread = (pixel), workgroup-uniform m
// selects which of q/k/v this block computes (m = blockIdx.x / 96).
// Output layout: [head][y][x][4] floats (q pre-scaled by 0.5*log2e).
// ---------------------------------------------------------------------------
__global__ __launch_bounds__(64) void qkv_conv_kernel(
    const float* __restrict__ x,
    const float* __restrict__ wq, const float* __restrict__ bq,
    const float* __restrict__ wk, const float* __restrict__ bk,
    const float* __restrict__ wv, const float* __restrict__ bv,
    float* __restrict__ qout, float* __restrict__ kout, float* __restrict__ vout)
{
    const int m   = blockIdx.x / 96;                 // 0=q 1=k 2=v (uniform)
    const int pix = (blockIdx.x % 96) * 64 + threadIdx.x;
    const int y   = pix / W_IMG;
    const int x0  = pix % W_IMG;

    const float* w = (m == 0) ? wq : (m == 1) ? wk : wv;
    const float* b = (m == 0) ? bq : (m == 1) ? bk : bv;

    float acc[DM];
    #pragma unroll
    for (int c = 0; c < DM; ++c) acc[c] = b[c];

    for (int dy = -1; dy <= 1; ++dy) {
        const int yy = y + dy;
        if (yy < 0 || yy >= H_IMG) continue;
        for (int dx = -1; dx <= 1; ++dx) {
            const int xc = x0 + dx;
            if (xc < 0 || xc >= W_IMG) continue;
            const float* xp = x + (yy * W_IMG + xc) * CIN;
            const float* wp = w + ((dy + 1) * 3 + (dx + 1)) * CIN * DM;
            for (int ci = 0; ci < CIN; ++ci) {
                const float xv = xp[ci];
                #pragma unroll
                for (int c = 0; c < DM; ++c)
                    acc[c] += xv * wp[ci * DM + c];
            }
        }
    }

    float* outp  = (m == 0) ? qout : (m == 1) ? kout : vout;
    const float s = (m == 0) ? Q_SCALE : 1.0f;

    #pragma unroll
    for (int h = 0; h < NH; ++h) {
        float4 val = make_float4(acc[h * 4 + 0] * s, acc[h * 4 + 1] * s,
                                 acc[h * 4 + 2] * s, acc[h * 4 + 3] * s);
        *reinterpret_cast<float4*>(outp + ((h * H_IMG + y) * W_IMG + x0) * 4) = val;
    }
}

// ---------------------------------------------------------------------------
// Kernel 2: local attention.  grid = 8 heads * 2 blocks * 12 qtiles = 192 WGs.
// Each thread owns one query; all lanes in a WG share (head, block) so K/V
// reads are wave-uniform (scalar loads).  Valid key set = rows 0..127, cols
// c0..c0+31 with c0 = g*16.  Single-pass softmax (exp2, no max needed).
// Writes att[y][x][h*4+d] (conv-ready channel order).
// ---------------------------------------------------------------------------
__global__ __launch_bounds__(256) void attn_kernel(
    const float* __restrict__ q,
    const float* __restrict__ k,
    const float* __restrict__ v,
    float* __restrict__ att)
{
    const int h  = blockIdx.x / 24;          // uniform
    const int g  = (blockIdx.x / 12) % 2;    // uniform
    const int qt = blockIdx.x % 12;          // uniform
    const int qid = qt * 256 + threadIdx.x;  // 0..3071 within (h,g)
    const int qy  = qid / 24;
    const int qx  = g * 24 + (qid % 24);

    const float4 qv = *reinterpret_cast<const float4*>(
        q + ((h * H_IMG + qy) * W_IMG + qx) * 4);

    const int c0 = g * 16;
    const float* kb = k + (h * H_IMG * W_IMG) * 4;
    const float* vb = v + (h * H_IMG * W_IMG) * 4;

    float a0 = 0.f, a1 = 0.f, a2 = 0.f, a3 = 0.f, ssum = 0.f;

    for (int r = 0; r < H_IMG; ++r) {
        const float* kr = kb + (r * W_IMG + c0) * 4;
        const float* vr = vb + (r * W_IMG + c0) * 4;
        #pragma unroll 8
        for (int j = 0; j < 32; ++j) {
            const float4 kk = *reinterpret_cast<const float4*>(kr + j * 4);
            const float4 vv = *reinterpret_cast<const float4*>(vr + j * 4);
            const float dot = qv.x * kk.x + qv.y * kk.y + qv.z * kk.z + qv.w * kk.w;
            const float e = exp2f(dot);      // q pre-scaled by 0.5*log2e
            ssum += e;
            a0 += e * vv.x; a1 += e * vv.y; a2 += e * vv.z; a3 += e * vv.w;
        }
    }

    const float inv = 1.0f / ssum;
    float4 o = make_float4(a0 * inv, a1 * inv, a2 * inv, a3 * inv);
    *reinterpret_cast<float4*>(att + (qy * W_IMG + qx) * DM + h * 4) = o;
}

// ---------------------------------------------------------------------------
// Kernel 3: output 3x3 SAME conv (32 -> 64 ch, no bias).
// thread = (pixel), uniform half = blockIdx.x/96 selects out-ch 32*half..+31.
// ---------------------------------------------------------------------------
__global__ __launch_bounds__(64) void out_conv_kernel(
    const float* __restrict__ att,
    const float* __restrict__ wo,
    float* __restrict__ out)
{
    const int half = blockIdx.x / 96;                // uniform
    const int pix  = (blockIdx.x % 96) * 64 + threadIdx.x;
    const int y    = pix / W_IMG;
    const int x0   = pix % W_IMG;

    float acc[32];
    #pragma unroll
    for (int c = 0; c < 32; ++c) acc[c] = 0.f;

    for (int dy = -1; dy <= 1; ++dy) {
        const int yy = y + dy;
        if (yy < 0 || yy >= H_IMG) continue;
        for (int dx = -1; dx <= 1; ++dx) {
            const int xc = x0 + dx;
            if (xc < 0 || xc >= W_IMG) continue;
            const float* ap = att + (yy * W_IMG + xc) * DM;
            const float* wp = wo + ((dy + 1) * 3 + (dx + 1)) * DM * 64 + half * 32;
            for (int ci = 0; ci < DM; ++ci) {
                const float xv = ap[ci];
                #pragma unroll
                for (int c = 0; c < 32; ++c)
                    acc[c] += xv * wp[ci * 64 + c];
            }
        }
    }

    float* op = out + (y * W_IMG + x0) * 64 + half * 32;
    #pragma unroll
    for (int c = 0; c < 32; ++c) op[c] = acc[c];
}

// ---------------------------------------------------------------------------
extern "C" void kernel_launch(void* const* d_in, const int* in_sizes, int n_in,
                              void* d_out, int out_size, void* d_ws, size_t ws_size,
                              hipStream_t stream)
{
    const float* x  = (const float*)d_in[0];
    const float* wq = (const float*)d_in[1];
    const float* bq = (const float*)d_in[2];
    const float* wk = (const float*)d_in[3];
    const float* bk = (const float*)d_in[4];
    const float* wv = (const float*)d_in[5];
    const float* bv = (const float*)d_in[6];
    const float* wo = (const float*)d_in[7];
    float* out = (float*)d_out;

    // workspace layout (floats)
    const size_t QKV = (size_t)NH * H_IMG * W_IMG * DH;  // 196608
    float* qbuf = (float*)d_ws;
    float* kbuf = qbuf + QKV;
    float* vbuf = kbuf + QKV;
    float* abuf = vbuf + QKV;                            // att [y][x][32]

    hipLaunchKernelGGL(qkv_conv_kernel, dim3(288), dim3(64), 0, stream,
                       x, wq, bq, wk, bk, wv, bv, qbuf, kbuf, vbuf);

    hipLaunchKernelGGL(attn_kernel, dim3(192), dim3(256), 0, stream,
                       qbuf, kbuf, vbuf, abuf);

    hipLaunchKernelGGL(out_conv_kernel, dim3(192), dim3(64), 0, stream,
                       abuf, wo, out);
}

// Round 2
// 143.059 us; speedup vs baseline: 2.6067x; 2.6067x over previous
//
#include <hip/hip_runtime.h>

#define H_IMG 128
#define W_IMG 48
#define CIN   64
#define DM    32
#define NH    8
#define DH    4
#define NPIX  (H_IMG * W_IMG)       // 6144
#define NQ    (NH * 2 * 3072)      // 49152 (head, halfband, query)

// 0.5 (dh^-0.5) * log2(e): fold exp->exp2 conversion into q
#define Q_SCALE 0.7213475204444817f

// ---------------------------------------------------------------------------
// Kernel 1: fused QKV 3x3 SAME conv. grid = 3(m) * 4(cgroup) * 24(pixgrp),
// block=256. Each thread: one pixel, 8 output channels. float4 x loads.
// Output layout: [head][y][x][4] floats (q pre-scaled by Q_SCALE).
// ---------------------------------------------------------------------------
__global__ __launch_bounds__(256) void qkv_conv_kernel(
    const float* __restrict__ x,
    const float* __restrict__ wq, const float* __restrict__ bq,
    const float* __restrict__ wk, const float* __restrict__ bk,
    const float* __restrict__ wv, const float* __restrict__ bv,
    float* __restrict__ qout, float* __restrict__ kout, float* __restrict__ vout)
{
    const int m   = blockIdx.x / 96;                 // 0=q 1=k 2=v (uniform)
    const int cg  = (blockIdx.x % 96) / 24;          // channel group (uniform)
    const int pix = (blockIdx.x % 24) * 256 + threadIdx.x;
    const int y   = pix / W_IMG;
    const int x0  = pix % W_IMG;

    const float* w = (m == 0) ? wq : (m == 1) ? wk : wv;
    const float* b = (m == 0) ? bq : (m == 1) ? bk : bv;

    float acc[8];
    #pragma unroll
    for (int j = 0; j < 8; ++j) acc[j] = b[cg * 8 + j];

    for (int dy = -1; dy <= 1; ++dy) {
        const int yy = y + dy;
        if (yy < 0 || yy >= H_IMG) continue;
        for (int dx = -1; dx <= 1; ++dx) {
            const int xc = x0 + dx;
            if (xc < 0 || xc >= W_IMG) continue;
            const float* xp = x + (yy * W_IMG + xc) * CIN;
            const float* wp = w + ((dy + 1) * 3 + (dx + 1)) * CIN * DM + cg * 8;
            for (int ci = 0; ci < CIN; ci += 4) {
                const float4 xv = *reinterpret_cast<const float4*>(xp + ci);
                #pragma unroll
                for (int j = 0; j < 8; ++j) {
                    acc[j] += xv.x * wp[(ci + 0) * DM + j];
                    acc[j] += xv.y * wp[(ci + 1) * DM + j];
                    acc[j] += xv.z * wp[(ci + 2) * DM + j];
                    acc[j] += xv.w * wp[(ci + 3) * DM + j];
                }
            }
        }
    }

    float* outp  = (m == 0) ? qout : (m == 1) ? kout : vout;
    const float s = (m == 0) ? Q_SCALE : 1.0f;

    #pragma unroll
    for (int hh = 0; hh < 2; ++hh) {
        const int h = cg * 2 + hh;
        float4 val = make_float4(acc[hh * 4 + 0] * s, acc[hh * 4 + 1] * s,
                                 acc[hh * 4 + 2] * s, acc[hh * 4 + 3] * s);
        *reinterpret_cast<float4*>(outp + ((h * H_IMG + y) * W_IMG + x0) * 4) = val;
    }
}

// ---------------------------------------------------------------------------
// Kernel 2a: local attention, split-K partials.
// grid = 8h * 2g * 12qt * S(seg); block=256, thread = one query.
// Segment handles key rows seg*(128/S) .. +(128/S), cols c0..c0+31 (c0=g*16).
// Partials (sum of exp, sum of exp*v) combine by addition across segments.
// ---------------------------------------------------------------------------
__global__ __launch_bounds__(256) void attn_partial_kernel(
    const float* __restrict__ q,
    const float* __restrict__ k,
    const float* __restrict__ v,
    float4* __restrict__ partA,     // [S][NQ]
    float*  __restrict__ partS,     // [S][NQ]
    int S)
{
    const int seg  = blockIdx.x % S;
    const int rest = blockIdx.x / S;
    const int qt   = rest % 12;
    const int g    = (rest / 12) % 2;
    const int h    = rest / 24;

    const int qid = qt * 256 + threadIdx.x;   // 0..3071
    const int qy  = qid / 24;
    const int qx  = g * 24 + (qid % 24);

    const float4 qv = *reinterpret_cast<const float4*>(
        q + ((h * H_IMG + qy) * W_IMG + qx) * 4);

    const int c0 = g * 16;
    const int rows = H_IMG / S;
    const int r0 = seg * rows;
    const float* kb = k + (h * H_IMG * W_IMG) * 4;
    const float* vb = v + (h * H_IMG * W_IMG) * 4;

    float a0 = 0.f, a1 = 0.f, a2 = 0.f, a3 = 0.f, ssum = 0.f;

    for (int r = r0; r < r0 + rows; ++r) {
        const float* kr = kb + (r * W_IMG + c0) * 4;
        const float* vr = vb + (r * W_IMG + c0) * 4;
        #pragma unroll 8
        for (int j = 0; j < 32; ++j) {
            const float4 kk = *reinterpret_cast<const float4*>(kr + j * 4);
            const float4 vv = *reinterpret_cast<const float4*>(vr + j * 4);
            const float dot = qv.x * kk.x + qv.y * kk.y + qv.z * kk.z + qv.w * kk.w;
            const float e = exp2f(dot);      // q pre-scaled by 0.5*log2e
            ssum += e;
            a0 += e * vv.x; a1 += e * vv.y; a2 += e * vv.z; a3 += e * vv.w;
        }
    }

    const int idx = ((h * 2 + g) * 3072 + qid);   // 0..NQ-1
    partA[seg * NQ + idx] = make_float4(a0, a1, a2, a3);
    partS[seg * NQ + idx] = ssum;
}

// ---------------------------------------------------------------------------
// Kernel 2b: combine split-K partials, normalize, write att[y][x][32]
// (channel order h*4+d, conv-ready).
// ---------------------------------------------------------------------------
__global__ __launch_bounds__(256) void attn_reduce_kernel(
    const float4* __restrict__ partA,
    const float*  __restrict__ partS,
    float* __restrict__ att,
    int S)
{
    const int idx = blockIdx.x * 256 + threadIdx.x;   // 0..NQ-1
    const int h   = idx / 6144;
    const int rem = idx % 6144;
    const int g   = rem / 3072;
    const int qid = rem % 3072;
    const int qy  = qid / 24;
    const int qx  = g * 24 + (qid % 24);

    float a0 = 0.f, a1 = 0.f, a2 = 0.f, a3 = 0.f, ssum = 0.f;
    for (int s = 0; s < S; ++s) {
        const float4 pa = partA[s * NQ + idx];
        a0 += pa.x; a1 += pa.y; a2 += pa.z; a3 += pa.w;
        ssum += partS[s * NQ + idx];
    }
    const float inv = 1.0f / ssum;
    *reinterpret_cast<float4*>(att + (qy * W_IMG + qx) * DM + h * 4) =
        make_float4(a0 * inv, a1 * inv, a2 * inv, a3 * inv);
}

// ---------------------------------------------------------------------------
// Kernel 3: output 3x3 SAME conv (32 -> 64 ch, no bias).
// grid = 8(cgroup) * 24(pixgrp), block=256; thread = pixel, 8 out channels.
// ---------------------------------------------------------------------------
__global__ __launch_bounds__(256) void out_conv_kernel(
    const float* __restrict__ att,
    const float* __restrict__ wo,
    float* __restrict__ out)
{
    const int cg  = blockIdx.x / 24;                 // uniform
    const int pix = (blockIdx.x % 24) * 256 + threadIdx.x;
    const int y   = pix / W_IMG;
    const int x0  = pix % W_IMG;

    float acc[8];
    #pragma unroll
    for (int j = 0; j < 8; ++j) acc[j] = 0.f;

    for (int dy = -1; dy <= 1; ++dy) {
        const int yy = y + dy;
        if (yy < 0 || yy >= H_IMG) continue;
        for (int dx = -1; dx <= 1; ++dx) {
            const int xc = x0 + dx;
            if (xc < 0 || xc >= W_IMG) continue;
            const float* ap = att + (yy * W_IMG + xc) * DM;
            const float* wp = wo + ((dy + 1) * 3 + (dx + 1)) * DM * 64 + cg * 8;
            for (int ci = 0; ci < DM; ci += 4) {
                const float4 xv = *reinterpret_cast<const float4*>(ap + ci);
                #pragma unroll
                for (int j = 0; j < 8; ++j) {
                    acc[j] += xv.x * wp[(ci + 0) * 64 + j];
                    acc[j] += xv.y * wp[(ci + 1) * 64 + j];
                    acc[j] += xv.z * wp[(ci + 2) * 64 + j];
                    acc[j] += xv.w * wp[(ci + 3) * 64 + j];
                }
            }
        }
    }

    float* op = out + (y * W_IMG + x0) * 64 + cg * 8;
    *reinterpret_cast<float4*>(op + 0) = make_float4(acc[0], acc[1], acc[2], acc[3]);
    *reinterpret_cast<float4*>(op + 4) = make_float4(acc[4], acc[5], acc[6], acc[7]);
}

// ---------------------------------------------------------------------------
extern "C" void kernel_launch(void* const* d_in, const int* in_sizes, int n_in,
                              void* d_out, int out_size, void* d_ws, size_t ws_size,
                              hipStream_t stream)
{
    const float* x  = (const float*)d_in[0];
    const float* wq = (const float*)d_in[1];
    const float* bq = (const float*)d_in[2];
    const float* wk = (const float*)d_in[3];
    const float* bk = (const float*)d_in[4];
    const float* wv = (const float*)d_in[5];
    const float* bv = (const float*)d_in[6];
    const float* wo = (const float*)d_in[7];
    float* out = (float*)d_out;

    // workspace layout (floats): kbuf, vbuf, qbuf(=abuf after attn), partA, partS
    const size_t QKV = (size_t)NH * H_IMG * W_IMG * DH;  // 196608
    float* kbuf = (float*)d_ws;
    float* vbuf = kbuf + QKV;
    float* qbuf = vbuf + QKV;        // reused as att buffer by the reduce
    float* part = qbuf + QKV;

    // pick largest split S in {8,4,2,1} that fits ws
    int S = 8;
    while (S > 1) {
        size_t need = (3 * QKV + (size_t)S * NQ * 5) * sizeof(float);
        if (need <= ws_size) break;
        S >>= 1;
    }
    float4* partA = (float4*)part;                 // S*NQ float4
    float*  partS = part + (size_t)S * NQ * 4;     // S*NQ floats
    float*  abuf  = qbuf;                          // alias (q dead after attn)

    hipLaunchKernelGGL(qkv_conv_kernel, dim3(288), dim3(256), 0, stream,
                       x, wq, bq, wk, bk, wv, bv, qbuf, kbuf, vbuf);

    hipLaunchKernelGGL(attn_partial_kernel, dim3(192 * S), dim3(256), 0, stream,
                       qbuf, kbuf, vbuf, partA, partS, S);

    hipLaunchKernelGGL(attn_reduce_kernel, dim3(NQ / 256), dim3(256), 0, stream,
                       partA, partS, abuf, S);

    hipLaunchKernelGGL(out_conv_kernel, dim3(192), dim3(256), 0, stream,
                       abuf, wo, out);
}